// Round 5
// baseline (1878.398 us; speedup 1.0000x reference)
//
#include <hip/hip_runtime.h>
#include <math.h>

#define BB 32768
#define EE 16
#define HH 128
#define KC 144        // EE + HH
#define NG 512        // 4*HH
#define OBS 8
#define NSTEP 19
#define TPB 256
#define ROWS 64       // rows per block
#define RPW 16        // rows per wave (4 waves/block)
#define NQ 36         // KC/4 k-quads

__device__ __forceinline__ float sigm(float x) {
    return __builtin_amdgcn_rcpf(1.0f + __expf(-x));
}
__device__ __forceinline__ float fast_tanh(float x) {
    float e = __expf(-2.0f * x);
    return (1.0f - e) * __builtin_amdgcn_rcpf(1.0f + e);
}

// Pack Wt[k][j*4+g] = (k<EE ? W_ih : W_hh)[col=g*128+j][k(-EE)]; bt[j*4+g] = b_ih+b_hh.
__global__ __launch_bounds__(256) void k_prep(
    const float* __restrict__ W_ih, const float* __restrict__ b_ih,
    const float* __restrict__ W_hh, const float* __restrict__ b_hh,
    float* __restrict__ Wt, float* __restrict__ bt)
{
    int idx = blockIdx.x * 256 + threadIdx.x;
    if (idx < KC * NG) {
        int k = idx >> 9, jg = idx & 511;
        int j = jg >> 2, g = jg & 3, col = g * HH + j;
        Wt[idx] = (k < EE) ? W_ih[col * EE + k] : W_hh[col * HH + (k - EE)];
    }
    if (idx < NG) {
        int j = idx >> 2, g = idx & 3, col = g * HH + j;
        bt[idx] = b_ih[col] + b_hh[col];
    }
}

__global__ __launch_bounds__(TPB, 2) void k_lstm(
    const float* __restrict__ obs,
    const float* __restrict__ W_emb, const float* __restrict__ b_emb,
    const float* __restrict__ Wt,    const float* __restrict__ bt,
    const float* __restrict__ W_out, const float* __restrict__ b_out,
    float* __restrict__ out)
{
    __shared__ float xh[ROWS * KC];      // per-wave-private row slices
    __shared__ float plpp[ROWS * 4];     // pl0 pl1 pp0 pp1 per row

    const int t  = threadIdx.x;
    const int tc = t & 63;               // lane
    const int tr = t >> 6;               // wave id 0..3
    const int rowL0 = tr * RPW;          // first local row of this wave
    const int row0  = blockIdx.x * ROWS + rowL0;

    // per-thread column bias (cols jg = tc*8 .. tc*8+7)
    float bias8[8];
    {
        float4 b0 = *reinterpret_cast<const float4*>(&bt[tc * 8]);
        float4 b1 = *reinterpret_cast<const float4*>(&bt[tc * 8 + 4]);
        bias8[0]=b0.x; bias8[1]=b0.y; bias8[2]=b0.z; bias8[3]=b0.w;
        bias8[4]=b1.x; bias8[5]=b1.y; bias8[6]=b1.z; bias8[7]=b1.w;
    }
    // readout weights for this lane's j-pair
    const float wo00 = W_out[0 * HH + tc * 2], wo01 = W_out[0 * HH + tc * 2 + 1];
    const float wo10 = W_out[1 * HH + tc * 2], wo11 = W_out[1 * HH + tc * 2 + 1];
    const float bo0 = b_out[0], bo1 = b_out[1];
    // embed weights for this lane's e-slot (e = tc&15)
    const int e_ = tc & 15;
    const float we0 = W_emb[2 * e_], we1 = W_emb[2 * e_ + 1], be = b_emb[e_];

    float c[RPW][2];
#pragma unroll
    for (int r = 0; r < RPW; r++) { c[r][0] = 0.0f; c[r][1] = 0.0f; }

    // zero own h region (wave-private; no barrier needed anywhere)
#pragma unroll
    for (int r = 0; r < RPW; r++) {
        xh[(rowL0 + r) * KC + EE + tc * 2]     = 0.0f;
        xh[(rowL0 + r) * KC + EE + tc * 2 + 1] = 0.0f;
    }

#pragma unroll 1
    for (int s = 0; s < NSTEP; s++) {
        // ---------- embed: relu(W_emb@delta + b_emb), rows wave-private ----------
#pragma unroll
        for (int pass = 0; pass < 4; pass++) {
            int rl = (tc >> 4) + pass * 4;          // local row 0..15
            int grow = row0 + rl;
            float d0, d1;
            if (s < OBS) {
                d0 = obs[(size_t)(s + 1) * BB * 2 + grow * 2]     - obs[(size_t)s * BB * 2 + grow * 2];
                d1 = obs[(size_t)(s + 1) * BB * 2 + grow * 2 + 1] - obs[(size_t)s * BB * 2 + grow * 2 + 1];
            } else {
                const float* p4 = &plpp[(rowL0 + rl) * 4];
                d0 = p4[0] - p4[2];
                d1 = p4[1] - p4[3];
            }
            float v = be + d0 * we0 + d1 * we1;
            xh[(rowL0 + rl) * KC + e_] = v > 0.0f ? v : 0.0f;
        }

        // ---------- gates: acc[r][cc], cc = jj*4+g ----------
        float acc[RPW][8];
#pragma unroll
        for (int r = 0; r < RPW; r++)
#pragma unroll
            for (int cc = 0; cc < 8; cc++) acc[r][cc] = bias8[cc];

#pragma unroll 1
        for (int kq = 0; kq < NQ; kq++) {
            // 4 consecutive k-rows of Wt for this lane's 8 cols (independent of r)
            const float* wrow = &Wt[(size_t)(kq * 4) * NG + tc * 8];
            float4 w0a = *reinterpret_cast<const float4*>(wrow);
            float4 w0b = *reinterpret_cast<const float4*>(wrow + 4);
            float4 w1a = *reinterpret_cast<const float4*>(wrow + NG);
            float4 w1b = *reinterpret_cast<const float4*>(wrow + NG + 4);
            float4 w2a = *reinterpret_cast<const float4*>(wrow + 2 * NG);
            float4 w2b = *reinterpret_cast<const float4*>(wrow + 2 * NG + 4);
            float4 w3a = *reinterpret_cast<const float4*>(wrow + 3 * NG);
            float4 w3b = *reinterpret_cast<const float4*>(wrow + 3 * NG + 4);
#pragma unroll
            for (int r = 0; r < RPW; r++) {
                float4 xv = *reinterpret_cast<const float4*>(&xh[(rowL0 + r) * KC + kq * 4]);
                acc[r][0] += xv.x * w0a.x; acc[r][1] += xv.x * w0a.y;
                acc[r][2] += xv.x * w0a.z; acc[r][3] += xv.x * w0a.w;
                acc[r][4] += xv.x * w0b.x; acc[r][5] += xv.x * w0b.y;
                acc[r][6] += xv.x * w0b.z; acc[r][7] += xv.x * w0b.w;

                acc[r][0] += xv.y * w1a.x; acc[r][1] += xv.y * w1a.y;
                acc[r][2] += xv.y * w1a.z; acc[r][3] += xv.y * w1a.w;
                acc[r][4] += xv.y * w1b.x; acc[r][5] += xv.y * w1b.y;
                acc[r][6] += xv.y * w1b.z; acc[r][7] += xv.y * w1b.w;

                acc[r][0] += xv.z * w2a.x; acc[r][1] += xv.z * w2a.y;
                acc[r][2] += xv.z * w2a.z; acc[r][3] += xv.z * w2a.w;
                acc[r][4] += xv.z * w2b.x; acc[r][5] += xv.z * w2b.y;
                acc[r][6] += xv.z * w2b.z; acc[r][7] += xv.z * w2b.w;

                acc[r][0] += xv.w * w3a.x; acc[r][1] += xv.w * w3a.y;
                acc[r][2] += xv.w * w3a.z; acc[r][3] += xv.w * w3a.w;
                acc[r][4] += xv.w * w3b.x; acc[r][5] += xv.w * w3b.y;
                acc[r][6] += xv.w * w3b.z; acc[r][7] += xv.w * w3b.w;
            }
        }

        // ---------- cell update + h writeback + readout partials ----------
        float red[RPW][2];
#pragma unroll
        for (int r = 0; r < RPW; r++) {
            float h0, h1;
            {
                float gi = sigm(acc[r][0]), gf = sigm(acc[r][1]);
                float gg = fast_tanh(acc[r][2]), go = sigm(acc[r][3]);
                float cn = gf * c[r][0] + gi * gg;
                c[r][0] = cn;
                h0 = go * fast_tanh(cn);
            }
            {
                float gi = sigm(acc[r][4]), gf = sigm(acc[r][5]);
                float gg = fast_tanh(acc[r][6]), go = sigm(acc[r][7]);
                float cn = gf * c[r][1] + gi * gg;
                c[r][1] = cn;
                h1 = go * fast_tanh(cn);
            }
            *reinterpret_cast<float2*>(&xh[(rowL0 + r) * KC + EE + tc * 2]) = make_float2(h0, h1);
            red[r][0] = h0 * wo00 + h1 * wo01;
            red[r][1] = h0 * wo10 + h1 * wo11;
        }

        // butterfly reduce over the 64 lanes (rows are wave-private)
#pragma unroll
        for (int mask = 1; mask < 64; mask <<= 1) {
#pragma unroll
            for (int r = 0; r < RPW; r++) {
                red[r][0] += __shfl_xor(red[r][0], mask, 64);
                red[r][1] += __shfl_xor(red[r][1], mask, 64);
            }
        }

        if (tc == 0) {
#pragma unroll
            for (int r = 0; r < RPW; r++) {
                int grow = row0 + r;
#pragma unroll
                for (int oc = 0; oc < 2; oc++) {
                    float base = (s < OBS)
                        ? obs[(size_t)(s + 1) * BB * 2 + grow * 2 + oc]
                        : plpp[(rowL0 + r) * 4 + oc];
                    float pos = base + red[r][oc] + (oc ? bo1 : bo0);
                    out[((size_t)s * BB + grow) * 2 + oc] = pos;
                    plpp[(rowL0 + r) * 4 + 2 + oc] = plpp[(rowL0 + r) * 4 + oc];  // pp <- pl
                    plpp[(rowL0 + r) * 4 + oc]     = pos;                          // pl <- pos
                }
            }
        }
        // no __syncthreads: all state (xh rows, plpp rows, c) is wave-private
    }
}

extern "C" void kernel_launch(void* const* d_in, const int* in_sizes, int n_in,
                              void* d_out, int out_size, void* d_ws, size_t ws_size,
                              hipStream_t stream)
{
    const float* obs   = (const float*)d_in[0];
    const float* W_emb = (const float*)d_in[1];
    const float* b_emb = (const float*)d_in[2];
    const float* W_ih  = (const float*)d_in[3];
    const float* b_ih  = (const float*)d_in[4];
    const float* W_hh  = (const float*)d_in[5];
    const float* b_hh  = (const float*)d_in[6];
    const float* W_out = (const float*)d_in[7];
    const float* b_out = (const float*)d_in[8];
    float* out = (float*)d_out;

    float* Wt = (float*)d_ws;                 // [144][512]
    float* bt = Wt + KC * NG;                 // [512]

    hipLaunchKernelGGL(k_prep, dim3((KC * NG + 255) / 256), dim3(256), 0, stream,
                       W_ih, b_ih, W_hh, b_hh, Wt, bt);

    hipLaunchKernelGGL(k_lstm, dim3(BB / ROWS), dim3(TPB), 0, stream,
                       obs, W_emb, b_emb, Wt, bt, W_out, b_out, out);
}